// Round 4
// baseline (365.201 us; speedup 1.0000x reference)
//
#include <hip/hip_runtime.h>
#include <stdint.h>
#include <math.h>

#define B_   4
#define T_   4096
#define BT_  16384
#define HID  2048
#define ED   256
#define HD   32
#define NH   8
#define K3   768   // packed K for split-precision key GEMM

typedef unsigned short u16;
typedef __attribute__((ext_vector_type(8))) short short8;
typedef __attribute__((ext_vector_type(4))) float f32x4;

typedef __attribute__((address_space(1))) void gvoid;
typedef __attribute__((address_space(3))) void lvoid;

__device__ __forceinline__ float bf2f(u16 h) {
    return __uint_as_float(((uint32_t)h) << 16);
}
__device__ __forceinline__ u16 f2bf(float f) {
    uint32_t u = __float_as_uint(f);
    u += 0x7FFFu + ((u >> 16) & 1u);   // round-to-nearest-even
    return (u16)(u >> 16);
}
__device__ __forceinline__ void gld_lds16(const void* g, void* l) {
    __builtin_amdgcn_global_load_lds((gvoid*)(uintptr_t)g, (lvoid*)(uintptr_t)l, 16, 0, 0);
}
__device__ __forceinline__ void BAR() {
    asm volatile("" ::: "memory");
    __builtin_amdgcn_s_barrier();
    asm volatile("" ::: "memory");
}

// ---------------- f32 -> bf16 convert ----------------
__global__ void k_cvt(const float* __restrict__ in, u16* __restrict__ out, int n) {
    int i = blockIdx.x * 256 + threadIdx.x;
    if (i < n) out[i] = f2bf(in[i]);
}

// ---- Wk -> packed [hi | lo | hi] rows of 768 (pairs with A3 = [hi | hi | lo]) ----
__global__ void k_cvt_wk3(const float* __restrict__ in, u16* __restrict__ out) {
    int i = blockIdx.x * 256 + threadIdx.x;   // over HID*ED
    int n = i >> 8, c = i & 255;
    float f = in[i];
    u16 h = f2bf(f);
    out[(size_t)n * K3 + c]       = h;
    out[(size_t)n * K3 + 256 + c] = f2bf(f - bf2f(h));
    out[(size_t)n * K3 + 512 + c] = h;
}

// ---------------- hash-embedding gather (f32) ----------------
__global__ void k_gather(const int* __restrict__ hashes, const int* __restrict__ offs,
                         const float* __restrict__ tab, float* __restrict__ E) {
    const int bt = blockIdx.x;
    const int tid = threadIdx.x;          // 256 = 8 heads x 32 dims
    const int head = tid >> 5, d = tid & 31;
    const int row = hashes[bt * NH + head] + offs[head];
    E[(size_t)bt * ED + tid] = tab[(size_t)row * HD + d];
}

// ---- conv + LN + silu + residual; writes A3 row = [e_hi | e_hi | e_lo] (768) ----
__global__ void k_conv(const float* __restrict__ E, const float* __restrict__ w,
                       const float* __restrict__ lng, const float* __restrict__ lnb,
                       u16* __restrict__ a3) {
    const int bt = blockIdx.x;
    const int b = bt >> 12;               // T_ = 4096
    const int t = bt & 4095;
    const int ch = threadIdx.x;           // 256
    float c = 0.f;
#pragma unroll
    for (int k = 0; k < 4; ++k) {
        int tt = t - 9 + 3 * k;           // taps at t-9, t-6, t-3, t
        if (tt >= 0)
            c += w[ch * 4 + k] * E[((size_t)(b * T_ + tt)) * ED + ch];
    }
    float s = c, s2 = c * c;
#pragma unroll
    for (int o = 32; o; o >>= 1) { s += __shfl_xor(s, o); s2 += __shfl_xor(s2, o); }
    __shared__ float red[8];
    const int wid = ch >> 6, lane = ch & 63;
    if (!lane) { red[wid] = s; red[4 + wid] = s2; }
    __syncthreads();
    s  = red[0] + red[1] + red[2] + red[3];
    s2 = red[4] + red[5] + red[6] + red[7];
    const float mean = s * (1.f / 256.f);
    const float var  = s2 * (1.f / 256.f) - mean * mean;
    float ln = (c - mean) * rsqrtf(var + 1e-5f) * lng[ch] + lnb[ch];
    float si = ln / (1.f + expf(-ln));    // silu
    float ev = E[(size_t)bt * ED + ch] + si;
    u16 h = f2bf(ev);
    a3[(size_t)bt * K3 + ch]       = h;
    a3[(size_t)bt * K3 + 256 + ch] = h;
    a3[(size_t)bt * K3 + 512 + ch] = f2bf(ev - bf2f(h));
}

// ---------------- per-row: q=LN(x), kln=LN(key f32), g, gamma (float4 loads) ----------------
__global__ void k_gamma(const float* __restrict__ x, const float* __restrict__ key,
                        const float* __restrict__ gk, const float* __restrict__ bk,
                        const float* __restrict__ gq, const float* __restrict__ bq,
                        float* __restrict__ gamma) {
    const int m = blockIdx.x;
    const int tid = threadIdx.x;          // 256 thr, 2 float4 each = 2048 floats
    const f32x4* xr = (const f32x4*)(x + (size_t)m * HID);
    const f32x4* kr = (const f32x4*)(key + (size_t)m * HID);
    f32x4 xs[2], ks[2];
    float sx = 0.f, sx2 = 0.f, sk = 0.f, sk2 = 0.f;
#pragma unroll
    for (int i = 0; i < 2; ++i) {
        f32x4 xv = xr[tid + i * 256]; xs[i] = xv;
        f32x4 kv = kr[tid + i * 256]; ks[i] = kv;
#pragma unroll
        for (int c = 0; c < 4; ++c) {
            sx += xv[c]; sx2 += xv[c] * xv[c];
            sk += kv[c]; sk2 += kv[c] * kv[c];
        }
    }
#pragma unroll
    for (int o = 32; o; o >>= 1) {
        sx += __shfl_xor(sx, o); sx2 += __shfl_xor(sx2, o);
        sk += __shfl_xor(sk, o); sk2 += __shfl_xor(sk2, o);
    }
    __shared__ float red[16];
    const int wid = tid >> 6, lane = tid & 63;
    if (!lane) { red[wid] = sx; red[4 + wid] = sx2; red[8 + wid] = sk; red[12 + wid] = sk2; }
    __syncthreads();
    sx  = red[0] + red[1] + red[2] + red[3];
    sx2 = red[4] + red[5] + red[6] + red[7];
    sk  = red[8] + red[9] + red[10] + red[11];
    sk2 = red[12] + red[13] + red[14] + red[15];
    const float inv = 1.f / (float)HID;
    const float mx = sx * inv, vx = sx2 * inv - mx * mx;
    const float mk = sk * inv, vk = sk2 * inv - mk * mk;
    const float rx = rsqrtf(vx + 1e-5f), rk = rsqrtf(vk + 1e-5f);
    float dot = 0.f;
#pragma unroll
    for (int i = 0; i < 2; ++i) {
        const int v4 = tid + i * 256;
        f32x4 g4 = ((const f32x4*)gq)[v4];
        f32x4 b4 = ((const f32x4*)bq)[v4];
        f32x4 gk4 = ((const f32x4*)gk)[v4];
        f32x4 bk4 = ((const f32x4*)bk)[v4];
#pragma unroll
        for (int c = 0; c < 4; ++c) {
            float q  = (xs[i][c] - mx) * rx * g4[c] + b4[c];
            float kl = (ks[i][c] - mk) * rk * gk4[c] + bk4[c];
            dot += q * kl;
        }
    }
#pragma unroll
    for (int o = 32; o; o >>= 1) dot += __shfl_xor(dot, o);
    __syncthreads();
    if (!lane) red[wid] = dot;
    __syncthreads();
    if (tid == 0) {
        float gd = (red[0] + red[1] + red[2] + red[3]) * 0.022097086912079608f; // 1/sqrt(2048)
        float sg = (gd > 0.f) ? 1.f : ((gd < 0.f) ? -1.f : 0.f);
        float sv = sqrtf(fmaxf(fabsf(gd), 1e-6f)) * sg;
        gamma[m] = 1.f / (1.f + expf(-sv));
    }
}

// ================= 256x256 / BK=64 8-phase bf16 MFMA GEMM =================
// C[m,n] = (rowscale[m]?) * sum_k A[m,k]*B[n,k]; A MxK (row stride lda),
// B NxK (row stride ldb), both bf16. 512 thr = 8 waves (2M x 4N), per-wave
// out 128x64. LDS 128 KiB dynamic: A dbuf [0,64K), B dbuf [64K,128K).
// Tile layout per buffer: 256 rows x 128B, XOR-swizzle byte^=((row&7)<<4)
// on BOTH stage-source column and ds_read (involution, rule 21).
// DEPTH FIX (r4): stage ALL 8 loads of tile t+2 at t.P4 (buffer p freed by
// t.P3 end-barrier); vmcnt(8) there drains tile t+1's loads, which were
// issued at (t-1).P4 — 4 phases (~700 cyc) earlier, covering HBM latency.
// Never vmcnt(0) in steady state (T4).
template <bool SCALE, bool OUTBF16>
__global__ __launch_bounds__(512, 2)
void gemm8(const u16* __restrict__ A, int lda, const u16* __restrict__ Bm, int ldb,
           const float* __restrict__ rowscale, void* __restrict__ Cout,
           int M, int N, int K) {
    extern __shared__ char smem[];
    const int tid = threadIdx.x, wid = tid >> 6, lane = tid & 63;
    const int l15 = lane & 15, lhi = lane >> 4;
    const int wr = wid >> 2, wc = wid & 3;

    // XCD-aware swizzle (nwg % 8 == 0 here)
    const int tiles_m = M >> 8;
    const int nwg = gridDim.x;
    const int cpx = nwg >> 3;
    const int id = blockIdx.x;
    const int swz = (id & 7) * cpx + (id >> 3);
    const int mblk = (swz % tiles_m) << 8;
    const int nblk = (swz / tiles_m) << 8;

    f32x4 acc[8][4];
#pragma unroll
    for (int i = 0; i < 8; ++i)
#pragma unroll
        for (int j = 0; j < 4; ++j) acc[i][j] = f32x4{0.f, 0.f, 0.f, 0.f};

    // stage source: thread tid stages 16B to linear LDS o = h*16K + r*8K + tid*16
    // row = o>>7 (128 B/row), src col pre-swizzled so LDS[o] = global at swz(o)
    const int srow = tid >> 3;
    const int scol = ((tid & 7) << 3) ^ ((srow & 7) << 3);
    const u16* aS[4];
    const u16* bS[4];
#pragma unroll
    for (int h = 0; h < 2; ++h)
#pragma unroll
        for (int r = 0; r < 2; ++r) {
            aS[h * 2 + r] = A  + (size_t)(mblk + h * 128 + r * 64 + srow) * lda + scol;
            bS[h * 2 + r] = Bm + (size_t)(nblk + h * 128 + r * 64 + srow) * ldb + scol;
        }
    const int wb = wid * 1024;   // wave-uniform byte base

    const int koff0 = (lhi * 16) ^ ((l15 & 7) << 4);
    const int koff1 = (64 + lhi * 16) ^ ((l15 & 7) << 4);

    short8 ar[4][2], br[2][2][2];

#define STAGE_TILE(tt) do { const int q_ = (tt) & 1; const int kk_ = (tt) << 6;      \
        char* da_ = smem + q_ * 32768 + wb;                                          \
        char* db_ = smem + 65536 + q_ * 32768 + wb;                                  \
        gld_lds16(aS[0] + kk_, da_);         gld_lds16(aS[1] + kk_, da_ + 8192);     \
        gld_lds16(aS[2] + kk_, da_ + 16384); gld_lds16(aS[3] + kk_, da_ + 24576);    \
        gld_lds16(bS[0] + kk_, db_);         gld_lds16(bS[1] + kk_, db_ + 8192);     \
        gld_lds16(bS[2] + kk_, db_ + 16384); gld_lds16(bS[3] + kk_, db_ + 24576);    \
    } while (0)
#define LDA_SUB(mh, p) do {                                                          \
        const char* ab_ = smem + (p) * 32768 + (wr * 128 + (mh) * 64) * 128;         \
        _Pragma("unroll") for (int fm = 0; fm < 4; ++fm) {                           \
            const char* rb_ = ab_ + (fm * 16 + l15) * 128;                           \
            ar[fm][0] = *(const short8*)(rb_ + koff0);                               \
            ar[fm][1] = *(const short8*)(rb_ + koff1); } } while (0)
#define LDB_SUB(nh, p) do {                                                          \
        const char* bb_ = smem + 65536 + (p) * 32768 + (wc * 64 + (nh) * 32) * 128;  \
        _Pragma("unroll") for (int fn = 0; fn < 2; ++fn) {                           \
            const char* rb_ = bb_ + (fn * 16 + l15) * 128;                           \
            br[nh][fn][0] = *(const short8*)(rb_ + koff0);                           \
            br[nh][fn][1] = *(const short8*)(rb_ + koff1); } } while (0)
#define MMQ(mh, nh) do { __builtin_amdgcn_s_setprio(1);                              \
        _Pragma("unroll") for (int fm = 0; fm < 4; ++fm)                             \
        _Pragma("unroll") for (int fn = 0; fn < 2; ++fn) {                           \
            acc[(mh) * 4 + fm][(nh) * 2 + fn] = __builtin_amdgcn_mfma_f32_16x16x32_bf16( \
                ar[fm][0], br[nh][fn][0], acc[(mh) * 4 + fm][(nh) * 2 + fn], 0, 0, 0);   \
            acc[(mh) * 4 + fm][(nh) * 2 + fn] = __builtin_amdgcn_mfma_f32_16x16x32_bf16( \
                ar[fm][1], br[nh][fn][1], acc[(mh) * 4 + fm][(nh) * 2 + fn], 0, 0, 0); } \
        __builtin_amdgcn_s_setprio(0); } while (0)

    // prologue: tiles 0 and 1 fully staged (16 loads); wait oldest 8 (tile 0)
    STAGE_TILE(0);
    STAGE_TILE(1);
    asm volatile("s_waitcnt vmcnt(8)" ::: "memory");
    BAR();

    const int nk = K >> 6;
    for (int t = 0; t < nk; ++t) {
        const int p = t & 1;
        // P1: A(mh0)+B(nh0) [12 ds_read]
        LDA_SUB(0, p); LDB_SUB(0, p);
        BAR(); MMQ(0, 0); BAR();
        // P2: B(nh1)
        LDB_SUB(1, p);
        BAR(); MMQ(0, 1); BAR();
        // P3: A(mh1)   (last reads of buffer p)
        LDA_SUB(1, p);
        BAR(); MMQ(1, 1); BAR();
        // P4: stage all of tile t+2 into buffer p (freed by P3 end-barrier);
        // counted wait drains tile t+1 (issued at (t-1).P4, 4 phases ago)
        if (t + 2 < nk) {
            STAGE_TILE(t + 2);
            asm volatile("s_waitcnt vmcnt(8)" ::: "memory");
        } else {
            asm volatile("s_waitcnt vmcnt(0)" ::: "memory");
        }
        BAR(); MMQ(1, 0); BAR();
    }
#undef STAGE_TILE
#undef LDA_SUB
#undef LDB_SUB
#undef MMQ

    // epilogue: D row=(lane>>4)*4+r, col=lane&15 per 16x16 fragment
#pragma unroll
    for (int mi = 0; mi < 8; ++mi) {
#pragma unroll
        for (int rr = 0; rr < 4; ++rr) {
            const int m = mblk + wr * 128 + mi * 16 + lhi * 4 + rr;
            const float sc = SCALE ? rowscale[m] : 1.0f;
#pragma unroll
            for (int nj = 0; nj < 4; ++nj) {
                const int n = nblk + wc * 64 + nj * 16 + l15;
                const float v = acc[mi][nj][rr] * sc;
                if (OUTBF16) ((u16*)Cout)[(size_t)m * N + n] = f2bf(v);
                else         ((float*)Cout)[(size_t)m * N + n] = v;
            }
        }
    }
}

extern "C" void kernel_launch(void* const* d_in, const int* in_sizes, int n_in,
                              void* d_out, int out_size, void* d_ws, size_t ws_size,
                              hipStream_t stream) {
    const float* x      = (const float*)d_in[0];
    const int*   hashes = (const int*)d_in[1];
    const int*   offs   = (const int*)d_in[2];
    const float* emb    = (const float*)d_in[3];
    const float* conv_w = (const float*)d_in[4];
    const float* lncg   = (const float*)d_in[5];
    const float* lncb   = (const float*)d_in[6];
    const float* Wk     = (const float*)d_in[7];
    const float* Wv     = (const float*)d_in[8];
    const float* Wo     = (const float*)d_in[9];
    const float* lnkg   = (const float*)d_in[10];
    const float* lnkb   = (const float*)d_in[11];
    const float* lnqg   = (const float*)d_in[12];
    const float* lnqb   = (const float*)d_in[13];

    // ws layout: E (16.8MB) and value (67MB) alias the key region (134MB);
    // lifetimes: E ends at k_conv; key written by GEMM1, dead after k_gamma;
    // value written by GEMM2. Total ws = 172 MB.
    char* p = (char*)d_ws;
    float* key   = (float*)p;
    float* E     = (float*)p;
    u16*   value = (u16*)p;  p += (size_t)BT_ * HID * 4;
    u16*   A3    = (u16*)p;  p += (size_t)BT_ * K3 * 2;
    u16*   Wk3   = (u16*)p;  p += (size_t)HID * K3 * 2;
    u16*   Wvb   = (u16*)p;  p += (size_t)HID * ED * 2;
    u16*   Wob   = (u16*)p;  p += (size_t)HID * HID * 2;
    float* gamma = (float*)p; p += (size_t)BT_ * 4;

    hipFuncSetAttribute((const void*)gemm8<false, false>,
                        hipFuncAttributeMaxDynamicSharedMemorySize, 131072);
    hipFuncSetAttribute((const void*)gemm8<true, true>,
                        hipFuncAttributeMaxDynamicSharedMemorySize, 131072);

    k_cvt<<<(HID * ED + 255) / 256, 256, 0, stream>>>(Wv, Wvb, HID * ED);
    k_cvt<<<(HID * HID + 255) / 256, 256, 0, stream>>>(Wo, Wob, HID * HID);
    k_cvt_wk3<<<(HID * ED) / 256, 256, 0, stream>>>(Wk, Wk3);
    k_gather<<<BT_, 256, 0, stream>>>(hashes, offs, emb, E);
    k_conv<<<BT_, 256, 0, stream>>>(E, conv_w, lncg, lncb, A3);
    // key = [ehi|ehi|elo] @ [Wkhi|Wklo|Wkhi]^T  (K'=768) -> f32
    gemm8<false, false><<<dim3((BT_ / 256) * (HID / 256)), 512, 131072, stream>>>(
        A3, K3, Wk3, K3, nullptr, key, BT_, HID, K3);
    k_gamma<<<BT_, 256, 0, stream>>>(x, key, lnkg, lnkb, lnqg, lnqb, gamma);
    // value = gamma * (ehi @ Wv^T)  (K=256) -> bf16 (overwrites dead key)
    gemm8<true, true><<<dim3((BT_ / 256) * (HID / 256)), 512, 131072, stream>>>(
        A3, K3, Wvb, ED, gamma, value, BT_, HID, ED);
    // out = value @ Wo^T  (K=2048) -> f32
    gemm8<false, false><<<dim3((BT_ / 256) * (HID / 256)), 512, 131072, stream>>>(
        value, HID, Wob, HID, nullptr, d_out, BT_, HID, HID);
}

// Round 5
// 355.604 us; speedup vs baseline: 1.0270x; 1.0270x over previous
//
#include <hip/hip_runtime.h>
#include <stdint.h>
#include <math.h>

#define B_   4
#define T_   4096
#define BT_  16384
#define HID  2048
#define ED   256
#define HD   32
#define NH   8
#define K3   768   // packed K for split-precision key GEMM

typedef unsigned short u16;
typedef __attribute__((ext_vector_type(8))) short short8;
typedef __attribute__((ext_vector_type(4))) float f32x4;

typedef __attribute__((address_space(1))) void gvoid;
typedef __attribute__((address_space(3))) void lvoid;

__device__ __forceinline__ float bf2f(u16 h) {
    return __uint_as_float(((uint32_t)h) << 16);
}
__device__ __forceinline__ u16 f2bf(float f) {
    uint32_t u = __float_as_uint(f);
    u += 0x7FFFu + ((u >> 16) & 1u);   // round-to-nearest-even
    return (u16)(u >> 16);
}
__device__ __forceinline__ void gld_lds16(const void* g, void* l) {
    __builtin_amdgcn_global_load_lds((gvoid*)(uintptr_t)g, (lvoid*)(uintptr_t)l, 16, 0, 0);
}
__device__ __forceinline__ void BAR() {
    asm volatile("" ::: "memory");
    __builtin_amdgcn_s_barrier();
    asm volatile("" ::: "memory");
}

// ---------------- f32 -> bf16 convert ----------------
__global__ void k_cvt(const float* __restrict__ in, u16* __restrict__ out, int n) {
    int i = blockIdx.x * 256 + threadIdx.x;
    if (i < n) out[i] = f2bf(in[i]);
}

// ---- Wk -> packed [hi | lo | hi] rows of 768 (pairs with A3 = [hi | hi | lo]) ----
__global__ void k_cvt_wk3(const float* __restrict__ in, u16* __restrict__ out) {
    int i = blockIdx.x * 256 + threadIdx.x;   // over HID*ED
    int n = i >> 8, c = i & 255;
    float f = in[i];
    u16 h = f2bf(f);
    out[(size_t)n * K3 + c]       = h;
    out[(size_t)n * K3 + 256 + c] = f2bf(f - bf2f(h));
    out[(size_t)n * K3 + 512 + c] = h;
}

// ---------------- hash-embedding gather (f32) ----------------
__global__ void k_gather(const int* __restrict__ hashes, const int* __restrict__ offs,
                         const float* __restrict__ tab, float* __restrict__ E) {
    const int bt = blockIdx.x;
    const int tid = threadIdx.x;          // 256 = 8 heads x 32 dims
    const int head = tid >> 5, d = tid & 31;
    const int row = hashes[bt * NH + head] + offs[head];
    E[(size_t)bt * ED + tid] = tab[(size_t)row * HD + d];
}

// ---- conv + LN + silu + residual; writes A3 row = [e_hi | e_hi | e_lo] (768) ----
__global__ void k_conv(const float* __restrict__ E, const float* __restrict__ w,
                       const float* __restrict__ lng, const float* __restrict__ lnb,
                       u16* __restrict__ a3) {
    const int bt = blockIdx.x;
    const int b = bt >> 12;               // T_ = 4096
    const int t = bt & 4095;
    const int ch = threadIdx.x;           // 256
    float c = 0.f;
#pragma unroll
    for (int k = 0; k < 4; ++k) {
        int tt = t - 9 + 3 * k;           // taps at t-9, t-6, t-3, t
        if (tt >= 0)
            c += w[ch * 4 + k] * E[((size_t)(b * T_ + tt)) * ED + ch];
    }
    float s = c, s2 = c * c;
#pragma unroll
    for (int o = 32; o; o >>= 1) { s += __shfl_xor(s, o); s2 += __shfl_xor(s2, o); }
    __shared__ float red[8];
    const int wid = ch >> 6, lane = ch & 63;
    if (!lane) { red[wid] = s; red[4 + wid] = s2; }
    __syncthreads();
    s  = red[0] + red[1] + red[2] + red[3];
    s2 = red[4] + red[5] + red[6] + red[7];
    const float mean = s * (1.f / 256.f);
    const float var  = s2 * (1.f / 256.f) - mean * mean;
    float ln = (c - mean) * rsqrtf(var + 1e-5f) * lng[ch] + lnb[ch];
    float si = ln / (1.f + expf(-ln));    // silu
    float ev = E[(size_t)bt * ED + ch] + si;
    u16 h = f2bf(ev);
    a3[(size_t)bt * K3 + ch]       = h;
    a3[(size_t)bt * K3 + 256 + ch] = h;
    a3[(size_t)bt * K3 + 512 + ch] = f2bf(ev - bf2f(h));
}

// ---------------- per-row: q=LN(x), kln=LN(key f32), g, gamma (float4 loads) ----------------
__global__ void k_gamma(const float* __restrict__ x, const float* __restrict__ key,
                        const float* __restrict__ gk, const float* __restrict__ bk,
                        const float* __restrict__ gq, const float* __restrict__ bq,
                        float* __restrict__ gamma) {
    const int m = blockIdx.x;
    const int tid = threadIdx.x;          // 256 thr, 2 float4 each = 2048 floats
    const f32x4* xr = (const f32x4*)(x + (size_t)m * HID);
    const f32x4* kr = (const f32x4*)(key + (size_t)m * HID);
    f32x4 xs[2], ks[2];
    float sx = 0.f, sx2 = 0.f, sk = 0.f, sk2 = 0.f;
#pragma unroll
    for (int i = 0; i < 2; ++i) {
        f32x4 xv = xr[tid + i * 256]; xs[i] = xv;
        f32x4 kv = kr[tid + i * 256]; ks[i] = kv;
#pragma unroll
        for (int c = 0; c < 4; ++c) {
            sx += xv[c]; sx2 += xv[c] * xv[c];
            sk += kv[c]; sk2 += kv[c] * kv[c];
        }
    }
#pragma unroll
    for (int o = 32; o; o >>= 1) {
        sx += __shfl_xor(sx, o); sx2 += __shfl_xor(sx2, o);
        sk += __shfl_xor(sk, o); sk2 += __shfl_xor(sk2, o);
    }
    __shared__ float red[16];
    const int wid = tid >> 6, lane = tid & 63;
    if (!lane) { red[wid] = sx; red[4 + wid] = sx2; red[8 + wid] = sk; red[12 + wid] = sk2; }
    __syncthreads();
    sx  = red[0] + red[1] + red[2] + red[3];
    sx2 = red[4] + red[5] + red[6] + red[7];
    sk  = red[8] + red[9] + red[10] + red[11];
    sk2 = red[12] + red[13] + red[14] + red[15];
    const float inv = 1.f / (float)HID;
    const float mx = sx * inv, vx = sx2 * inv - mx * mx;
    const float mk = sk * inv, vk = sk2 * inv - mk * mk;
    const float rx = rsqrtf(vx + 1e-5f), rk = rsqrtf(vk + 1e-5f);
    float dot = 0.f;
#pragma unroll
    for (int i = 0; i < 2; ++i) {
        const int v4 = tid + i * 256;
        f32x4 g4 = ((const f32x4*)gq)[v4];
        f32x4 b4 = ((const f32x4*)bq)[v4];
        f32x4 gk4 = ((const f32x4*)gk)[v4];
        f32x4 bk4 = ((const f32x4*)bk)[v4];
#pragma unroll
        for (int c = 0; c < 4; ++c) {
            float q  = (xs[i][c] - mx) * rx * g4[c] + b4[c];
            float kl = (ks[i][c] - mk) * rk * gk4[c] + bk4[c];
            dot += q * kl;
        }
    }
#pragma unroll
    for (int o = 32; o; o >>= 1) dot += __shfl_xor(dot, o);
    __syncthreads();
    if (!lane) red[wid] = dot;
    __syncthreads();
    if (tid == 0) {
        float gd = (red[0] + red[1] + red[2] + red[3]) * 0.022097086912079608f; // 1/sqrt(2048)
        float sg = (gd > 0.f) ? 1.f : ((gd < 0.f) ? -1.f : 0.f);
        float sv = sqrtf(fmaxf(fabsf(gd), 1e-6f)) * sg;
        gamma[m] = 1.f / (1.f + expf(-sv));
    }
}

// ================= 256x256 / BK=64, 2-barriers-per-K-tile bf16 MFMA GEMM =================
// C[m,n] = (rowscale[m]?) * sum_k A[m,k]*B[n,k]; A MxK (lda), B NxK (ldb), bf16.
// 512 thr = 8 waves (2M x 4N), per-wave out 128x64. LDS 128 KiB dynamic:
// A dbuf [0,64K), B dbuf [64K,128K). 256 rows x 128B per buffer, XOR-swizzle
// byte^=((row&7)<<4) on BOTH stage-source column and ds_read (involution).
//
// r5 SCHEDULE FIX: the r3/r4 8-barrier loop serialized {LDS drain}->{MFMA}
// inside every phase (measured MfmaUtil 37% == predicted 40% from that model).
// Now only 2 barriers per K-tile (AITER pattern, ~32 MFMA per barrier):
//   reads+MMQs (no barriers; compiler's counted lgkm interleaves, waves slip)
//   BAR#1  — every wave's reads of buf p are complete (MFMA operands forced
//            the lgkm wait before its MMQs issued), so p may be overwritten
//   STAGE(t+2) into p; vmcnt(8) drains OWN tile-t+1 loads (issued 1 tile ago)
//   BAR#2  — all waves' t+1 loads landed; publish
// Never vmcnt(0) in steady state (T4).
template <bool SCALE, bool OUTBF16>
__global__ __launch_bounds__(512, 2)
void gemm8(const u16* __restrict__ A, int lda, const u16* __restrict__ Bm, int ldb,
           const float* __restrict__ rowscale, void* __restrict__ Cout,
           int M, int N, int K) {
    extern __shared__ char smem[];
    const int tid = threadIdx.x, wid = tid >> 6, lane = tid & 63;
    const int l15 = lane & 15, lhi = lane >> 4;
    const int wr = wid >> 2, wc = wid & 3;

    // XCD-aware swizzle (nwg % 8 == 0 here)
    const int tiles_m = M >> 8;
    const int nwg = gridDim.x;
    const int cpx = nwg >> 3;
    const int id = blockIdx.x;
    const int swz = (id & 7) * cpx + (id >> 3);
    const int mblk = (swz % tiles_m) << 8;
    const int nblk = (swz / tiles_m) << 8;

    f32x4 acc[8][4];
#pragma unroll
    for (int i = 0; i < 8; ++i)
#pragma unroll
        for (int j = 0; j < 4; ++j) acc[i][j] = f32x4{0.f, 0.f, 0.f, 0.f};

    // stage source: thread tid stages 16B to linear LDS o = h*16K + r*8K + tid*16
    // row = o>>7 (128 B/row), src col pre-swizzled so LDS[o] = global at swz(o)
    const int srow = tid >> 3;
    const int scol = ((tid & 7) << 3) ^ ((srow & 7) << 3);
    const u16* aS[4];
    const u16* bS[4];
#pragma unroll
    for (int h = 0; h < 2; ++h)
#pragma unroll
        for (int r = 0; r < 2; ++r) {
            aS[h * 2 + r] = A  + (size_t)(mblk + h * 128 + r * 64 + srow) * lda + scol;
            bS[h * 2 + r] = Bm + (size_t)(nblk + h * 128 + r * 64 + srow) * ldb + scol;
        }
    const int wb = wid * 1024;   // wave-uniform byte base

    const int koff0 = (lhi * 16) ^ ((l15 & 7) << 4);
    const int koff1 = (64 + lhi * 16) ^ ((l15 & 7) << 4);

    short8 ar[4][2], br[2][2][2];

#define STAGE_TILE(tt) do { const int q_ = (tt) & 1; const int kk_ = (tt) << 6;      \
        char* da_ = smem + q_ * 32768 + wb;                                          \
        char* db_ = smem + 65536 + q_ * 32768 + wb;                                  \
        gld_lds16(aS[0] + kk_, da_);         gld_lds16(aS[1] + kk_, da_ + 8192);     \
        gld_lds16(aS[2] + kk_, da_ + 16384); gld_lds16(aS[3] + kk_, da_ + 24576);    \
        gld_lds16(bS[0] + kk_, db_);         gld_lds16(bS[1] + kk_, db_ + 8192);     \
        gld_lds16(bS[2] + kk_, db_ + 16384); gld_lds16(bS[3] + kk_, db_ + 24576);    \
    } while (0)
#define LDA_SUB(mh, p) do {                                                          \
        const char* ab_ = smem + (p) * 32768 + (wr * 128 + (mh) * 64) * 128;         \
        _Pragma("unroll") for (int fm = 0; fm < 4; ++fm) {                           \
            const char* rb_ = ab_ + (fm * 16 + l15) * 128;                           \
            ar[fm][0] = *(const short8*)(rb_ + koff0);                               \
            ar[fm][1] = *(const short8*)(rb_ + koff1); } } while (0)
#define LDB_SUB(nh, p) do {                                                          \
        const char* bb_ = smem + 65536 + (p) * 32768 + (wc * 64 + (nh) * 32) * 128;  \
        _Pragma("unroll") for (int fn = 0; fn < 2; ++fn) {                           \
            const char* rb_ = bb_ + (fn * 16 + l15) * 128;                           \
            br[nh][fn][0] = *(const short8*)(rb_ + koff0);                           \
            br[nh][fn][1] = *(const short8*)(rb_ + koff1); } } while (0)
#define MMQ(mh, nh) do { __builtin_amdgcn_s_setprio(1);                              \
        _Pragma("unroll") for (int fm = 0; fm < 4; ++fm)                             \
        _Pragma("unroll") for (int fn = 0; fn < 2; ++fn) {                           \
            acc[(mh) * 4 + fm][(nh) * 2 + fn] = __builtin_amdgcn_mfma_f32_16x16x32_bf16( \
                ar[fm][0], br[nh][fn][0], acc[(mh) * 4 + fm][(nh) * 2 + fn], 0, 0, 0);   \
            acc[(mh) * 4 + fm][(nh) * 2 + fn] = __builtin_amdgcn_mfma_f32_16x16x32_bf16( \
                ar[fm][1], br[nh][fn][1], acc[(mh) * 4 + fm][(nh) * 2 + fn], 0, 0, 0); } \
        __builtin_amdgcn_s_setprio(0); } while (0)

    // prologue: tiles 0 and 1 fully staged (16 loads); wait oldest 8 (tile 0)
    STAGE_TILE(0);
    STAGE_TILE(1);
    asm volatile("s_waitcnt vmcnt(8)" ::: "memory");
    BAR();

    const int nk = K >> 6;
    for (int t = 0; t < nk; ++t) {
        const int p = t & 1;
        // one K-tile of reads+MFMA, no internal barriers: compiler interleaves
        // via counted lgkmcnt; the 2 waves/SIMD slip freely
        LDA_SUB(0, p); LDB_SUB(0, p);
        MMQ(0, 0);
        LDB_SUB(1, p);
        MMQ(0, 1);
        LDA_SUB(1, p);
        MMQ(1, 1);
        MMQ(1, 0);
        BAR();   // all waves done reading buffer p (operand lgkm waits guarantee per-wave)
        if (t + 2 < nk) {
            STAGE_TILE(t + 2);   // overwrite buffer p
            asm volatile("s_waitcnt vmcnt(8)" ::: "memory");   // drain own tile t+1
        } else {
            asm volatile("s_waitcnt vmcnt(0)" ::: "memory");   // tail drain
        }
        BAR();   // publish tile t+1
    }
#undef STAGE_TILE
#undef LDA_SUB
#undef LDB_SUB
#undef MMQ

    // epilogue: D row=(lane>>4)*4+r, col=lane&15 per 16x16 fragment
#pragma unroll
    for (int mi = 0; mi < 8; ++mi) {
#pragma unroll
        for (int rr = 0; rr < 4; ++rr) {
            const int m = mblk + wr * 128 + mi * 16 + lhi * 4 + rr;
            const float sc = SCALE ? rowscale[m] : 1.0f;
#pragma unroll
            for (int nj = 0; nj < 4; ++nj) {
                const int n = nblk + wc * 64 + nj * 16 + l15;
                const float v = acc[mi][nj][rr] * sc;
                if (OUTBF16) ((u16*)Cout)[(size_t)m * N + n] = f2bf(v);
                else         ((float*)Cout)[(size_t)m * N + n] = v;
            }
        }
    }
}

extern "C" void kernel_launch(void* const* d_in, const int* in_sizes, int n_in,
                              void* d_out, int out_size, void* d_ws, size_t ws_size,
                              hipStream_t stream) {
    const float* x      = (const float*)d_in[0];
    const int*   hashes = (const int*)d_in[1];
    const int*   offs   = (const int*)d_in[2];
    const float* emb    = (const float*)d_in[3];
    const float* conv_w = (const float*)d_in[4];
    const float* lncg   = (const float*)d_in[5];
    const float* lncb   = (const float*)d_in[6];
    const float* Wk     = (const float*)d_in[7];
    const float* Wv     = (const float*)d_in[8];
    const float* Wo     = (const float*)d_in[9];
    const float* lnkg   = (const float*)d_in[10];
    const float* lnkb   = (const float*)d_in[11];
    const float* lnqg   = (const float*)d_in[12];
    const float* lnqb   = (const float*)d_in[13];

    // ws layout: E (16.8MB) and value (67MB) alias the key region (134MB);
    // lifetimes: E ends at k_conv; key written by GEMM1, dead after k_gamma;
    // value written by GEMM2. Total ws = 172 MB.
    char* p = (char*)d_ws;
    float* key   = (float*)p;
    float* E     = (float*)p;
    u16*   value = (u16*)p;  p += (size_t)BT_ * HID * 4;
    u16*   A3    = (u16*)p;  p += (size_t)BT_ * K3 * 2;
    u16*   Wk3   = (u16*)p;  p += (size_t)HID * K3 * 2;
    u16*   Wvb   = (u16*)p;  p += (size_t)HID * ED * 2;
    u16*   Wob   = (u16*)p;  p += (size_t)HID * HID * 2;
    float* gamma = (float*)p; p += (size_t)BT_ * 4;

    hipFuncSetAttribute((const void*)gemm8<false, false>,
                        hipFuncAttributeMaxDynamicSharedMemorySize, 131072);
    hipFuncSetAttribute((const void*)gemm8<true, true>,
                        hipFuncAttributeMaxDynamicSharedMemorySize, 131072);

    k_cvt<<<(HID * ED + 255) / 256, 256, 0, stream>>>(Wv, Wvb, HID * ED);
    k_cvt<<<(HID * HID + 255) / 256, 256, 0, stream>>>(Wo, Wob, HID * HID);
    k_cvt_wk3<<<(HID * ED) / 256, 256, 0, stream>>>(Wk, Wk3);
    k_gather<<<BT_, 256, 0, stream>>>(hashes, offs, emb, E);
    k_conv<<<BT_, 256, 0, stream>>>(E, conv_w, lncg, lncb, A3);
    // key = [ehi|ehi|elo] @ [Wkhi|Wklo|Wkhi]^T  (K'=768) -> f32
    gemm8<false, false><<<dim3((BT_ / 256) * (HID / 256)), 512, 131072, stream>>>(
        A3, K3, Wk3, K3, nullptr, key, BT_, HID, K3);
    k_gamma<<<BT_, 256, 0, stream>>>(x, key, lnkg, lnkb, lnqg, lnqb, gamma);
    // value = gamma * (ehi @ Wv^T)  (K=256) -> bf16 (overwrites dead key)
    gemm8<true, true><<<dim3((BT_ / 256) * (HID / 256)), 512, 131072, stream>>>(
        A3, K3, Wvb, ED, gamma, value, BT_, HID, ED);
    // out = value @ Wo^T  (K=2048) -> f32
    gemm8<false, false><<<dim3((BT_ / 256) * (HID / 256)), 512, 131072, stream>>>(
        value, HID, Wob, HID, nullptr, d_out, BT_, HID, HID);
}